// Round 1
// baseline (395.132 us; speedup 1.0000x reference)
//
#include <hip/hip_runtime.h>
#include <hip/hip_bf16.h>
#include <stdint.h>

#define IN_F   4096
#define OUT_F  4096
#define BATCH  4096

// ---------------------------------------------------------------------------
// Types for MFMA fragments (gfx950 16x16x32 bf16: A/B = 8 bf16, C/D = 4 f32)
// ---------------------------------------------------------------------------
typedef __bf16 bf16x8_t __attribute__((ext_vector_type(8)));
typedef float  f32x4_t  __attribute__((ext_vector_type(4)));

#define AS_GLOBAL(p) ((const __attribute__((address_space(1))) void*)(p))
#define AS_LDS(p)    ((__attribute__((address_space(3))) void*)(p))

__device__ __forceinline__ unsigned short f32_to_bf16_rne(float f) {
    union { float f; uint32_t u; } v; v.f = f;
    uint32_t u = v.u;
    // round-to-nearest-even; inputs are finite (mask in {0,1}, W bounded, x gaussian)
    u += 0x7FFFu + ((u >> 16) & 1u);
    return (unsigned short)(u >> 16);
}

// ---------------------------------------------------------------------------
// Pre-pass: xb = bf16(x), wb = bf16(W * M).  Both arrays are 4096*4096 elems.
// ---------------------------------------------------------------------------
__global__ void convert_kernel(const float* __restrict__ x,
                               const float* __restrict__ w,
                               const float* __restrict__ m,
                               unsigned short* __restrict__ xb,
                               unsigned short* __restrict__ wb) {
    const int64_t n4 = (int64_t)OUT_F * IN_F / 4;  // == BATCH*IN_F/4 as well
    int64_t i = (int64_t)blockIdx.x * blockDim.x + threadIdx.x;
    const int64_t stride = (int64_t)gridDim.x * blockDim.x;
    for (; i < n4; i += stride) {
        float4 xv = ((const float4*)x)[i];
        float4 wv = ((const float4*)w)[i];
        float4 mv = ((const float4*)m)[i];
        ushort4 xo, wo;
        xo.x = f32_to_bf16_rne(xv.x);
        xo.y = f32_to_bf16_rne(xv.y);
        xo.z = f32_to_bf16_rne(xv.z);
        xo.w = f32_to_bf16_rne(xv.w);
        wo.x = f32_to_bf16_rne(wv.x * mv.x);
        wo.y = f32_to_bf16_rne(wv.y * mv.y);
        wo.z = f32_to_bf16_rne(wv.z * mv.z);
        wo.w = f32_to_bf16_rne(wv.w * mv.w);
        ((ushort4*)xb)[i] = xo;
        ((ushort4*)wb)[i] = wo;
    }
}

// ---------------------------------------------------------------------------
// bf16 MFMA GEMM, m97 structure: y[b][o] = sum_k xb[b][k]*wb[o][k] + bias[o]
// BM=BN=128, BK=32; 256 threads = 4 waves in 2x2 grid, each wave 64x64 via
// 4x4 frags of 16x16x32 MFMA. global_load_lds width=16 for staging.
// ---------------------------------------------------------------------------
#define BM 128
#define BN 128
#define BK 32

__global__ __launch_bounds__(256)
void gemm_bt_bias_kernel(const unsigned short* __restrict__ A,   // [BATCH][IN_F] bf16 bits
                         const unsigned short* __restrict__ B,   // [OUT_F][IN_F] bf16 bits
                         const float* __restrict__ bias,         // [OUT_F]
                         float* __restrict__ C) {                // [BATCH][OUT_F]
    // No padding: global_load_lds requires LDS dest = wave-uniform base + lane*16.
    __shared__ __align__(16) unsigned short sA[BM * BK];  // 8 KiB
    __shared__ __align__(16) unsigned short sB[BN * BK];  // 8 KiB

    const int t    = threadIdx.x;
    const int wv   = t >> 6;       // wave 0..3
    const int lane = t & 63;
    const int quad = lane >> 4;    // 0..3
    const int l16  = lane & 15;

    const int bm = blockIdx.y * BM;   // batch-row base
    const int bn = blockIdx.x * BN;   // out-col base

    const int wr = wv >> 1;           // wave row in 2x2 grid
    const int wc = wv & 1;            // wave col

    // Staging map: thread t, round r loads 16B = 8 bf16 at
    //   row = t/4 + r*64, col = (t%4)*8  of the 128x32 tile.
    const int srow = t >> 2;
    const int scol = (t & 3) * 8;
    const unsigned short* gA = A + (int64_t)(bm + srow) * IN_F + scol;
    const unsigned short* gB = B + (int64_t)(bn + srow) * IN_F + scol;

    f32x4_t acc[4][4];
#pragma unroll
    for (int mi = 0; mi < 4; ++mi)
#pragma unroll
        for (int ni = 0; ni < 4; ++ni)
            acc[mi][ni] = (f32x4_t){0.f, 0.f, 0.f, 0.f};

    for (int k0 = 0; k0 < IN_F; k0 += BK) {
        __syncthreads();   // previous tile fully consumed before overwrite
#pragma unroll
        for (int r = 0; r < 2; ++r) {
            // LDS base is wave-uniform; HW scatters lane i at base + i*16.
            __builtin_amdgcn_global_load_lds(
                AS_GLOBAL(gA + (int64_t)r * 64 * IN_F + k0),
                AS_LDS((char*)sA + r * 4096 + wv * 1024), 16, 0, 0);
            __builtin_amdgcn_global_load_lds(
                AS_GLOBAL(gB + (int64_t)r * 64 * IN_F + k0),
                AS_LDS((char*)sB + r * 4096 + wv * 1024), 16, 0, 0);
        }
        __syncthreads();   // drains vmcnt: tile visible to all waves

        bf16x8_t af[4], bf[4];
#pragma unroll
        for (int mi = 0; mi < 4; ++mi)
            af[mi] = *(const bf16x8_t*)(sA + (wr * 64 + mi * 16 + l16) * BK + quad * 8);
#pragma unroll
        for (int ni = 0; ni < 4; ++ni)
            bf[ni] = *(const bf16x8_t*)(sB + (wc * 64 + ni * 16 + l16) * BK + quad * 8);

#pragma unroll
        for (int mi = 0; mi < 4; ++mi)
#pragma unroll
            for (int ni = 0; ni < 4; ++ni)
                acc[mi][ni] = __builtin_amdgcn_mfma_f32_16x16x32_bf16(
                    af[mi], bf[ni], acc[mi][ni], 0, 0, 0);
    }

    // Epilogue: C/D layout col = lane&15 (n), row = quad*4 + reg (m).
    float bv[4];
#pragma unroll
    for (int ni = 0; ni < 4; ++ni)
        bv[ni] = bias[bn + wc * 64 + ni * 16 + l16];

#pragma unroll
    for (int mi = 0; mi < 4; ++mi) {
        const int row0 = bm + wr * 64 + mi * 16 + quad * 4;
#pragma unroll
        for (int ni = 0; ni < 4; ++ni) {
            const int col = bn + wc * 64 + ni * 16 + l16;
#pragma unroll
            for (int reg = 0; reg < 4; ++reg)
                C[(int64_t)(row0 + reg) * OUT_F + col] = acc[mi][ni][reg] + bv[ni];
        }
    }
}

// ---------------------------------------------------------------------------
// Fallback (only if workspace is unexpectedly small): plain fp32 tiled GEMM.
// ---------------------------------------------------------------------------
__global__ void fallback_gemm_kernel(const float* __restrict__ x,
                                     const float* __restrict__ w,
                                     const float* __restrict__ bias,
                                     const float* __restrict__ m,
                                     float* __restrict__ y) {
    __shared__ float sx[16][17];
    __shared__ float sw[16][17];
    const int tx = threadIdx.x, ty = threadIdx.y;
    const int row = blockIdx.y * 16 + ty;   // batch
    const int col = blockIdx.x * 16 + tx;   // out
    float acc = 0.f;
    for (int k0 = 0; k0 < IN_F; k0 += 16) {
        sx[ty][tx] = x[(int64_t)row * IN_F + k0 + tx];
        const int64_t widx = (int64_t)(blockIdx.x * 16 + ty) * IN_F + k0 + tx;
        sw[ty][tx] = w[widx] * m[widx];
        __syncthreads();
#pragma unroll
        for (int kk = 0; kk < 16; ++kk)
            acc += sx[ty][kk] * sw[tx][kk];
        __syncthreads();
    }
    y[(int64_t)row * OUT_F + col] = acc + bias[col];
}

// ---------------------------------------------------------------------------
extern "C" void kernel_launch(void* const* d_in, const int* in_sizes, int n_in,
                              void* d_out, int out_size, void* d_ws, size_t ws_size,
                              hipStream_t stream) {
    const float* x    = (const float*)d_in[0];   // [BATCH, IN_F]
    const float* w    = (const float*)d_in[1];   // [OUT_F, IN_F]
    const float* bias = (const float*)d_in[2];   // [OUT_F]
    const float* m    = (const float*)d_in[3];   // [OUT_F, IN_F]
    float* y = (float*)d_out;                    // [BATCH, OUT_F]

    const size_t need = (size_t)2 * (size_t)OUT_F * (size_t)IN_F * sizeof(unsigned short); // 64 MiB

    if (ws_size >= need) {
        unsigned short* xb = (unsigned short*)d_ws;
        unsigned short* wb = xb + (size_t)BATCH * IN_F;

        convert_kernel<<<2048, 256, 0, stream>>>(x, w, m, xb, wb);

        dim3 grid(OUT_F / BN, BATCH / BM);   // 32 x 32
        gemm_bt_bias_kernel<<<grid, 256, 0, stream>>>(xb, wb, bias, y);
    } else {
        dim3 grid(OUT_F / 16, BATCH / 16);
        dim3 block(16, 16);
        fallback_gemm_kernel<<<grid, block, 0, stream>>>(x, w, bias, m, y);
    }
}

// Round 2
// 341.789 us; speedup vs baseline: 1.1561x; 1.1561x over previous
//
#include <hip/hip_runtime.h>
#include <hip/hip_bf16.h>
#include <stdint.h>

#define IN_F   4096
#define OUT_F  4096
#define BATCH  4096

typedef __bf16 bf16x8_t __attribute__((ext_vector_type(8)));
typedef float  f32x4_t  __attribute__((ext_vector_type(4)));

#define AS_GLOBAL(p) ((const __attribute__((address_space(1))) void*)(p))
#define AS_LDS(p)    ((__attribute__((address_space(3))) void*)(p))

__device__ __forceinline__ unsigned short f32_to_bf16_rne(float f) {
    union { float f; uint32_t u; } v; v.f = f;
    uint32_t u = v.u;
    u += 0x7FFFu + ((u >> 16) & 1u);
    return (unsigned short)(u >> 16);
}

// ---------------------------------------------------------------------------
// Pre-pass: xb = bf16(x), wb = bf16(W * M). Exact-size launch: one float4
// triple per thread (16384 blocks x 256 threads = 4096*4096/4 positions).
// ---------------------------------------------------------------------------
__global__ __launch_bounds__(256)
void convert_kernel(const float* __restrict__ x,
                    const float* __restrict__ w,
                    const float* __restrict__ m,
                    unsigned short* __restrict__ xb,
                    unsigned short* __restrict__ wb) {
    const int64_t i = (int64_t)blockIdx.x * 256 + threadIdx.x;
    float4 xv = ((const float4*)x)[i];
    float4 wv = ((const float4*)w)[i];
    float4 mv = ((const float4*)m)[i];
    ushort4 xo, wo;
    xo.x = f32_to_bf16_rne(xv.x);
    xo.y = f32_to_bf16_rne(xv.y);
    xo.z = f32_to_bf16_rne(xv.z);
    xo.w = f32_to_bf16_rne(xv.w);
    wo.x = f32_to_bf16_rne(wv.x * mv.x);
    wo.y = f32_to_bf16_rne(wv.y * mv.y);
    wo.z = f32_to_bf16_rne(wv.z * mv.z);
    wo.w = f32_to_bf16_rne(wv.w * mv.w);
    ((ushort4*)xb)[i] = xo;
    ((ushort4*)wb)[i] = wo;
}

// ---------------------------------------------------------------------------
// bf16 MFMA GEMM: y[b][o] = sum_k xb[b][k]*wb[o][k] + bias[o]
// BM=BN=128, BK=64; 256 threads = 4 waves (2x2), each wave 64x64 via 4x4
// frags of 16x16x32 MFMA, two k-subtiles per LDS tile.
// LDS rows are 128 B (32 banks), so the 16-B chunk index is XOR-swizzled by
// (row&7) on the GLOBAL side (global_load_lds LDS dest must stay linear);
// frag reads undo the swizzle -> conflict-free (8-cyc minimum per b128).
// ---------------------------------------------------------------------------
#define BM 128
#define BN 128
#define BK 64

__global__ __launch_bounds__(256)
void gemm_bt_bias_kernel(const unsigned short* __restrict__ A,   // [BATCH][IN_F]
                         const unsigned short* __restrict__ B,   // [OUT_F][IN_F]
                         const float* __restrict__ bias,         // [OUT_F]
                         float* __restrict__ C) {                // [BATCH][OUT_F]
    __shared__ __align__(16) unsigned short sA[BM * BK];  // 16 KiB
    __shared__ __align__(16) unsigned short sB[BN * BK];  // 16 KiB

    const int t    = threadIdx.x;
    const int wv   = t >> 6;
    const int lane = t & 63;
    const int quad = lane >> 4;    // 0..3
    const int l16  = lane & 15;

    const int bm = blockIdx.y * BM;
    const int bn = blockIdx.x * BN;

    const int wr = wv >> 1;
    const int wc = wv & 1;

    // Staging map (per round r of 4): thread t loads 16 B for
    //   row = r*32 + t/8,  elem-col = 8 * ((t&7) ^ ((t>>3)&7))   [swizzled]
    // which lands at LDS linear byte offset r*4096 + t*16 (row-major swizzled).
    const int srow = t >> 3;
    const int scol = 8 * ((t & 7) ^ ((t >> 3) & 7));
    const unsigned short* gA = A + (int64_t)(bm + srow) * IN_F + scol;
    const unsigned short* gB = B + (int64_t)(bn + srow) * IN_F + scol;

    f32x4_t acc[4][4];
#pragma unroll
    for (int mi = 0; mi < 4; ++mi)
#pragma unroll
        for (int ni = 0; ni < 4; ++ni)
            acc[mi][ni] = (f32x4_t){0.f, 0.f, 0.f, 0.f};

    for (int k0 = 0; k0 < IN_F; k0 += BK) {
        __syncthreads();   // previous tile fully consumed
#pragma unroll
        for (int r = 0; r < 4; ++r) {
            __builtin_amdgcn_global_load_lds(
                AS_GLOBAL(gA + (int64_t)r * 32 * IN_F + k0),
                AS_LDS((char*)sA + r * 4096 + wv * 1024 + (lane * 16)), 16, 0, 0);
            __builtin_amdgcn_global_load_lds(
                AS_GLOBAL(gB + (int64_t)r * 32 * IN_F + k0),
                AS_LDS((char*)sB + r * 4096 + wv * 1024 + (lane * 16)), 16, 0, 0);
        }
        __syncthreads();   // vmcnt drain: tile visible

#pragma unroll
        for (int ks = 0; ks < 2; ++ks) {
            bf16x8_t af[4], bf[4];
#pragma unroll
            for (int mi = 0; mi < 4; ++mi) {
                const int row = wr * 64 + mi * 16 + l16;
                const int ch  = (ks * 4 + quad) ^ (row & 7);
                af[mi] = *(const bf16x8_t*)(sA + row * BK + ch * 8);
            }
#pragma unroll
            for (int ni = 0; ni < 4; ++ni) {
                const int row = wc * 64 + ni * 16 + l16;
                const int ch  = (ks * 4 + quad) ^ (row & 7);
                bf[ni] = *(const bf16x8_t*)(sB + row * BK + ch * 8);
            }
#pragma unroll
            for (int mi = 0; mi < 4; ++mi)
#pragma unroll
                for (int ni = 0; ni < 4; ++ni)
                    acc[mi][ni] = __builtin_amdgcn_mfma_f32_16x16x32_bf16(
                        af[mi], bf[ni], acc[mi][ni], 0, 0, 0);
        }
    }

    // Epilogue: C/D layout col = lane&15 (n), row = quad*4 + reg (m).
    float bv[4];
#pragma unroll
    for (int ni = 0; ni < 4; ++ni)
        bv[ni] = bias[bn + wc * 64 + ni * 16 + l16];

#pragma unroll
    for (int mi = 0; mi < 4; ++mi) {
        const int row0 = bm + wr * 64 + mi * 16 + quad * 4;
#pragma unroll
        for (int ni = 0; ni < 4; ++ni) {
            const int col = bn + wc * 64 + ni * 16 + l16;
#pragma unroll
            for (int reg = 0; reg < 4; ++reg)
                C[(int64_t)(row0 + reg) * OUT_F + col] = acc[mi][ni][reg] + bv[ni];
        }
    }
}

// ---------------------------------------------------------------------------
// Fallback (workspace too small): plain fp32 tiled GEMM.
// ---------------------------------------------------------------------------
__global__ void fallback_gemm_kernel(const float* __restrict__ x,
                                     const float* __restrict__ w,
                                     const float* __restrict__ bias,
                                     const float* __restrict__ m,
                                     float* __restrict__ y) {
    __shared__ float sx[16][17];
    __shared__ float sw[16][17];
    const int tx = threadIdx.x, ty = threadIdx.y;
    const int row = blockIdx.y * 16 + ty;
    const int col = blockIdx.x * 16 + tx;
    float acc = 0.f;
    for (int k0 = 0; k0 < IN_F; k0 += 16) {
        sx[ty][tx] = x[(int64_t)row * IN_F + k0 + tx];
        const int64_t widx = (int64_t)(blockIdx.x * 16 + ty) * IN_F + k0 + tx;
        sw[ty][tx] = w[widx] * m[widx];
        __syncthreads();
#pragma unroll
        for (int kk = 0; kk < 16; ++kk)
            acc += sx[ty][kk] * sw[tx][kk];
        __syncthreads();
    }
    y[(int64_t)row * OUT_F + col] = acc + bias[col];
}

// ---------------------------------------------------------------------------
extern "C" void kernel_launch(void* const* d_in, const int* in_sizes, int n_in,
                              void* d_out, int out_size, void* d_ws, size_t ws_size,
                              hipStream_t stream) {
    const float* x    = (const float*)d_in[0];
    const float* w    = (const float*)d_in[1];
    const float* bias = (const float*)d_in[2];
    const float* m    = (const float*)d_in[3];
    float* y = (float*)d_out;

    const size_t need = (size_t)2 * (size_t)OUT_F * (size_t)IN_F * sizeof(unsigned short);

    if (ws_size >= need) {
        unsigned short* xb = (unsigned short*)d_ws;
        unsigned short* wb = xb + (size_t)BATCH * IN_F;

        // exact-size: 4096*4096/4 float4 positions / 256 threads = 16384 blocks
        convert_kernel<<<16384, 256, 0, stream>>>(x, w, m, xb, wb);

        dim3 grid(OUT_F / BN, BATCH / BM);   // 32 x 32
        gemm_bt_bias_kernel<<<grid, 256, 0, stream>>>(xb, wb, bias, y);
    } else {
        dim3 grid(OUT_F / 16, BATCH / 16);
        dim3 block(16, 16);
        fallback_gemm_kernel<<<grid, block, 0, stream>>>(x, w, bias, m, y);
    }
}